// Round 12
// baseline (162.040 us; speedup 1.0000x reference)
//
#include <hip/hip_runtime.h>
#include <hip/hip_bf16.h>

#define T_TOK 2048
#define NE 768
#define DFF 3072
#define NEXP 8
#define ROWS_PAD 4480
#define MAX_TILES 40
#define NB_G1 (MAX_TILES * 12)          // 480
#define NB_T2 (NEXP * (DFF / 64) * (NE / 64))   // 4608
#define NB_RT 512
#define NB_T1 (NEXP * (NE / 64) * (DFF / 64))   // 4608

typedef __attribute__((ext_vector_type(8))) __bf16 bf16x8;
typedef __attribute__((ext_vector_type(4))) __bf16 bf16x4;
typedef __attribute__((ext_vector_type(4))) float f32x4;

__device__ __forceinline__ float gelu_tanh(float v) {
  float u = 0.7978845608028654f * (v + 0.044715f * v * v * v);
  float e = __expf(-2.0f * fabsf(u));
  float t = (1.0f - e) / (1.0f + e);
  t = copysignf(t, u);
  return 0.5f * v * (1.0f + t);
}

// chunk involution: XOR low-3 of 16B-chunk id with bits [5:3] (row-pair id)
__device__ __forceinline__ int swz_chunk(int c) {
  return (c & ~7) | ((c & 7) ^ ((c >> 3) & 7));
}

// ---------------- router body: one wave per token ----------------
__device__ __forceinline__ void router_body(const float* __restrict__ x,
                                            const float* __restrict__ noise,
                                            const float* __restrict__ rw,
                                            int* __restrict__ sel, float* __restrict__ wgt,
                                            int bid) {
  int tok  = (bid * 256 + (int)threadIdx.x) >> 6;
  int lane = threadIdx.x & 63;
  const float* xr = x + (size_t)tok * NE;
  float acc[NEXP];
#pragma unroll
  for (int e = 0; e < NEXP; e++) acc[e] = 0.f;
  for (int d = lane; d < NE; d += 64) {
    float xv = xr[d];
#pragma unroll
    for (int e = 0; e < NEXP; e++) acc[e] += xv * rw[e * NE + d];
  }
#pragma unroll
  for (int e = 0; e < NEXP; e++) {
#pragma unroll
    for (int off = 32; off > 0; off >>= 1) acc[e] += __shfl_xor(acc[e], off);
  }
  if (lane == 0) {
    float lg[NEXP];
#pragma unroll
    for (int e = 0; e < NEXP; e++) lg[e] = acc[e] + noise[tok * NEXP + e];
    int i0 = 0;
#pragma unroll
    for (int e = 1; e < NEXP; e++) if (lg[e] > lg[i0]) i0 = e;
    int i1 = (i0 == 0) ? 1 : 0;
#pragma unroll
    for (int e = 0; e < NEXP; e++) if (e != i0 && lg[e] > lg[i1]) i1 = e;
    float ex = __expf(lg[i1] - lg[i0]);
    float w0 = 1.f / (1.f + ex);
    sel[tok * 2]     = i0; sel[tok * 2 + 1] = i1;
    wgt[tok * 2]     = w0; wgt[tok * 2 + 1] = 1.f - w0;
  }
}

// ---------------- transpose body: fp32 [e][K][N] -> bf16 [e][N][K], 64x64 tile ----------------
__device__ __forceinline__ void transpose_body(const float* __restrict__ src,
                                               __hip_bfloat16* __restrict__ dst,
                                               int K, int N, int bid, char* smem) {
  __hip_bfloat16* tile = (__hip_bfloat16*)smem;   // 64*72 bf16 = 9216 B
  int ntk = K >> 6, ntn = N >> 6;
  int e = bid / (ntk * ntn);
  int rem = bid % (ntk * ntn);
  int tk = rem / ntn, tn = rem % ntn;
  const float* s = src + (size_t)e * K * N + (size_t)(tk * 64) * N + tn * 64;
  int t = threadIdx.x;
  int a = t & 15;
  int kp = t >> 4;
#pragma unroll
  for (int i = 0; i < 2; i++) {
    int k = 2 * kp + 32 * i;
    float4 v0 = *reinterpret_cast<const float4*>(&s[(size_t)k * N + 4 * a]);
    float4 v1 = *reinterpret_cast<const float4*>(&s[(size_t)(k + 1) * N + 4 * a]);
    const float* p0 = &v0.x; const float* p1 = &v1.x;
#pragma unroll
    for (int j = 0; j < 4; j++) {
      __hip_bfloat162 p;
      p.x = __float2bfloat16(p0[j]); p.y = __float2bfloat16(p1[j]);
      *reinterpret_cast<__hip_bfloat162*>(&tile[(4 * a + j) * 72 + k]) = p;
    }
  }
  __syncthreads();
  int n = t >> 3, g = t & 7;
  __hip_bfloat16* d = dst + (size_t)e * N * K + (size_t)(tn * 64) * K + tk * 64;
#pragma unroll
  for (int i = 0; i < 2; i++) {
    int row = n + 32 * i;
    bf16x8 v = *reinterpret_cast<const bf16x8*>(&tile[row * 72 + g * 8]);
    *reinterpret_cast<bf16x8*>(&d[(size_t)row * K + g * 8]) = v;
  }
}

// ---------------- grouped GEMM body: 128x256 tile, BK=32, 4 waves,
//   3-buffer depth-2 counted-vmcnt, chunk-involution swizzle, LDS-bounce epilogue ----
// A: [rows][K] bf16. Bt: [E][N][K] bf16. DST: [SPLITS][ROWS_PAD][N] bf16.
// MODE 0: DST = bf16(gelu(acc+bias)); MODE 1: DST = bf16(acc + (sp==0 ? bias : 0)).
template <int K, int N, int MODE, int SPLITS>
__device__ __forceinline__ void gemm_body(
    const __hip_bfloat16* __restrict__ A, const __hip_bfloat16* __restrict__ Bt,
    const float* __restrict__ bias, __hip_bfloat16* __restrict__ DST,
    const int* __restrict__ offs, const int* __restrict__ tiles,
    const int* __restrict__ ntl, char* smem, int bid) {
  constexpr int NT = N / 256;
  constexpr int KS = K / SPLITS;
  constexpr int NS = KS / 32;
  int nt = bid % NT;
  int r1 = bid / NT;
  int sp = r1 % SPLITS;
  int ti = r1 / SPLITS;
  if (ti >= *ntl) return;
  int e = tiles[ti * 2], row0 = tiles[ti * 2 + 1];
  int rend = offs[e + 1];
  int n0 = nt * 256;
  int kbeg = sp * KS;

  int tid = threadIdx.x;
  int w = tid >> 6, l = tid & 63;
  int wr = w >> 1, wc = w & 1;          // 2x2 waves; wave tile 64 rows x 128 cols
  int r16 = l & 15, q = l >> 4;

  f32x4 acc[4][8];
#pragma unroll
  for (int m = 0; m < 4; m++)
#pragma unroll
    for (int n = 0; n < 8; n++) acc[m][n] = (f32x4){0.f, 0.f, 0.f, 0.f};

  const __hip_bfloat16* Bte = Bt + (size_t)e * N * K;

  // buffer b: A 8KB (128x32) at smem+b*24576, B 16KB (256x32) at +8192
  auto STAGE = [&](int b, int k0) {
    char* cA = smem + b * 24576;
    char* cB = cA + 8192;
#pragma unroll
    for (int i = 0; i < 2; i++) {       // A: 512 chunks
      int Lc = tid + 256 * i;
      int fc = swz_chunk(Lc);
      int row = fc >> 2, p = fc & 3;
      const __hip_bfloat16* ga = A + (size_t)(row0 + row) * K + k0 + p * 8;
      __builtin_amdgcn_global_load_lds(
          (const __attribute__((address_space(1))) void*)ga,
          (__attribute__((address_space(3))) void*)(cA + Lc * 16), 16, 0, 0);
    }
#pragma unroll
    for (int i = 0; i < 4; i++) {       // B: 1024 chunks
      int Lc = tid + 256 * i;
      int fc = swz_chunk(Lc);
      int row = fc >> 2, p = fc & 3;
      const __hip_bfloat16* gb = Bte + (size_t)(n0 + row) * K + k0 + p * 8;
      __builtin_amdgcn_global_load_lds(
          (const __attribute__((address_space(1))) void*)gb,
          (__attribute__((address_space(3))) void*)(cB + Lc * 16), 16, 0, 0);
    }
  };

  STAGE(0, kbeg);
  if (NS > 1) STAGE(1, kbeg + 32);
  for (int t = 0; t < NS; t++) {
    if (t + 2 < NS) {
      STAGE((t + 2) % 3, kbeg + (t + 2) * 32);
      asm volatile("s_waitcnt vmcnt(12)" ::: "memory");  // stage t done; t+1,t+2 in flight
    } else if (t + 1 < NS) {
      asm volatile("s_waitcnt vmcnt(6)" ::: "memory");
    } else {
      asm volatile("s_waitcnt vmcnt(0)" ::: "memory");
    }
    __builtin_amdgcn_s_barrier();
    __builtin_amdgcn_sched_barrier(0);
    const char* cA = smem + (t % 3) * 24576;
    const char* cB = cA + 8192;
    bf16x8 aF[4], bF[8];
#pragma unroll
    for (int m = 0; m < 4; m++) {
      int row = wr * 64 + m * 16 + r16;
      aF[m] = *reinterpret_cast<const bf16x8*>(cA + swz_chunk(row * 4 + q) * 16);
    }
#pragma unroll
    for (int n = 0; n < 8; n++) {
      int row = wc * 128 + n * 16 + r16;
      bF[n] = *reinterpret_cast<const bf16x8*>(cB + swz_chunk(row * 4 + q) * 16);
    }
#pragma unroll
    for (int m = 0; m < 4; m++)
#pragma unroll
      for (int n = 0; n < 8; n++)
        acc[m][n] = __builtin_amdgcn_mfma_f32_16x16x32_bf16(aF[m], bF[n], acc[m][n], 0, 0, 0);
    __builtin_amdgcn_s_barrier();
  }

  // ---- epilogue via LDS bounce: 2 halves of 64 rows x 256 cols (f32 [64][264]) ----
  float* ldsF = (float*)smem;           // 67.6 KB of 72 KB
  __hip_bfloat16* dst = DST + (size_t)sp * ROWS_PAD * N;
#pragma unroll
  for (int hh = 0; hh < 2; hh++) {
    __syncthreads();
    if (wr == hh) {
#pragma unroll
      for (int m = 0; m < 4; m++)
#pragma unroll
        for (int n = 0; n < 8; n++)
#pragma unroll
          for (int rg = 0; rg < 4; rg++)
            ldsF[(m * 16 + q * 4 + rg) * 264 + wc * 128 + n * 16 + r16] = acc[m][n][rg];
    }
    __syncthreads();
#pragma unroll
    for (int i = 0; i < 8; i++) {
      int s = tid + 256 * i;            // 4096 spans of 8 f32 = 64 rows x 32 spans
      int r = s >> 5, c8 = s & 31;
      int rr = row0 + hh * 64 + r;
      if (rr < rend) {
        const float* src = &ldsF[r * 264 + c8 * 8];
        float4 v0 = *reinterpret_cast<const float4*>(src);
        float4 v1 = *reinterpret_cast<const float4*>(src + 4);
        const float* bp = &bias[e * N + n0 + c8 * 8];
        float4 bb0 = *reinterpret_cast<const float4*>(bp);
        float4 bb1 = *reinterpret_cast<const float4*>(bp + 4);
        float vv[8]  = {v0.x, v0.y, v0.z, v0.w, v1.x, v1.y, v1.z, v1.w};
        float bbv[8] = {bb0.x, bb0.y, bb0.z, bb0.w, bb1.x, bb1.y, bb1.z, bb1.w};
        bf16x8 o;
#pragma unroll
        for (int j = 0; j < 8; j++) {
          float val;
          if (MODE == 0) val = gelu_tanh(vv[j] + bbv[j]);
          else           val = vv[j] + (sp == 0 ? bbv[j] : 0.f);
          o[j] = (__bf16)__float2bfloat16(val);
        }
        *reinterpret_cast<bf16x8*>(&dst[(size_t)rr * N + n0 + c8 * 8]) = o;
      }
    }
  }
}

// ---------------- kernel: router (512 blocks) | transpose w1 (4608 blocks) ----------------
__global__ __launch_bounds__(256) void router_t1_kernel(
    const float* __restrict__ x, const float* __restrict__ noise,
    const float* __restrict__ rw, int* __restrict__ sel, float* __restrict__ wgt,
    const float* __restrict__ w1, __hip_bfloat16* __restrict__ wt1) {
  __shared__ __align__(16) char smem[9216];
  if (blockIdx.x < NB_RT) router_body(x, noise, rw, sel, wgt, blockIdx.x);
  else transpose_body(w1, wt1, NE, DFF, blockIdx.x - NB_RT, smem);
}

// ---------------- assignment + worklist: 1 block, 8 waves, two-pass ----------------
__global__ void assign_kernel(const int* __restrict__ sel,
                              int* __restrict__ offs, int* __restrict__ pair_tok,
                              int* __restrict__ slot_of, int* __restrict__ tiles,
                              int* __restrict__ ntl) {
  __shared__ int scnt[NEXP];
  __shared__ int soff[NEXP + 1];
  int e = threadIdx.x >> 6;
  int lane = threadIdx.x & 63;

  int count = 0;
  for (int t0 = 0; t0 < T_TOK; t0 += 64) {
    int t = t0 + lane;
    bool m = (sel[t * 2] == e) | (sel[t * 2 + 1] == e);
    count += __popcll(__ballot(m));
  }
  if (lane == 0) scnt[e] = count;
  __syncthreads();

  if (threadIdx.x == 0) {
    int s = 0;
    for (int k = 0; k < NEXP; k++) { soff[k] = s; s += scnt[k]; }
    soff[NEXP] = s;
    for (int i = 0; i <= NEXP; i++) offs[i] = soff[i];
    int k2 = 0;
    for (int k = 0; k < NEXP; k++)
      for (int r = soff[k]; r < soff[k + 1]; r += 128) {
        tiles[k2 * 2] = k; tiles[k2 * 2 + 1] = r; k2++;
      }
    *ntl = k2;
  }
  __syncthreads();

  int base = soff[e];
  for (int t0 = 0; t0 < T_TOK; t0 += 64) {
    int t = t0 + lane;
    int s0 = sel[t * 2], s1 = sel[t * 2 + 1];
    bool m0 = (s0 == e), m1 = (s1 == e);
    bool m = m0 | m1;
    unsigned long long mask = __ballot(m);
    int pos = __popcll(mask & ((1ull << lane) - 1ull));
    if (m) {
      int slot = base + pos;
      pair_tok[slot] = t;
      slot_of[t * 2 + (m0 ? 0 : 1)] = slot;
    }
    base += __popcll(mask);
  }
}

// ---------------- gather x rows -> bf16 ----------------
__global__ void gather_kernel(const float* __restrict__ x, const int* __restrict__ pair_tok,
                              __hip_bfloat16* __restrict__ xg) {
  int r = blockIdx.x;
  int tok = pair_tok[r];
  const float4* s = (const float4*)(x + (size_t)tok * NE);
  __hip_bfloat16* d = xg + (size_t)r * NE;
  int t = threadIdx.x;
  if (t < NE / 4) {
    float4 v = s[t];
    bf16x4 o;
    o[0] = (__bf16)__float2bfloat16(v.x); o[1] = (__bf16)__float2bfloat16(v.y);
    o[2] = (__bf16)__float2bfloat16(v.z); o[3] = (__bf16)__float2bfloat16(v.w);
    *reinterpret_cast<bf16x4*>(&d[t * 4]) = o;
  }
}

// ---------------- kernel: GEMM1 (480 blocks) | transpose w2 (4608 blocks) ----------------
__global__ __launch_bounds__(256) void g1_t2_kernel(
    const __hip_bfloat16* __restrict__ xg, const __hip_bfloat16* __restrict__ wt1,
    const float* __restrict__ b1, __hip_bfloat16* __restrict__ h,
    const int* __restrict__ offs, const int* __restrict__ tiles,
    const int* __restrict__ ntl,
    const float* __restrict__ w2, __hip_bfloat16* __restrict__ wt2) {
  __shared__ __align__(16) char smem[73728];
  if (blockIdx.x < NB_G1)
    gemm_body<NE, DFF, 0, 1>(xg, wt1, b1, h, offs, tiles, ntl, smem, blockIdx.x);
  else
    transpose_body(w2, wt2, DFF, NE, blockIdx.x - NB_G1, smem);
}

// ---------------- kernel: GEMM2 split-K x4 ----------------
__global__ __launch_bounds__(256) void g2_kernel(
    const __hip_bfloat16* __restrict__ h, const __hip_bfloat16* __restrict__ wt2,
    const float* __restrict__ b2, __hip_bfloat16* __restrict__ yb,
    const int* __restrict__ offs, const int* __restrict__ tiles,
    const int* __restrict__ ntl) {
  __shared__ __align__(16) char smem[73728];
  gemm_body<DFF, NE, 1, 4>(h, wt2, b2, yb, offs, tiles, ntl, smem, blockIdx.x);
}

// ---------------- combine ----------------
template <int SPLITS>
__global__ void combine_kernel(const __hip_bfloat16* __restrict__ yb,
                               const int* __restrict__ slot_of,
                               const float* __restrict__ wgt,
                               float* __restrict__ out) {
  int t = blockIdx.x;
  int d = threadIdx.x;
  int s0 = slot_of[2 * t], s1 = slot_of[2 * t + 1];
  float w0 = wgt[2 * t], w1 = wgt[2 * t + 1];
  float a0 = 0.f, a1 = 0.f, a2 = 0.f, a3 = 0.f;
#pragma unroll
  for (int sp = 0; sp < SPLITS; sp++) {
    bf16x4 p = reinterpret_cast<const bf16x4*>(yb + (size_t)(sp * ROWS_PAD + s0) * NE)[d];
    bf16x4 r = reinterpret_cast<const bf16x4*>(yb + (size_t)(sp * ROWS_PAD + s1) * NE)[d];
    a0 += w0 * (float)p[0] + w1 * (float)r[0];
    a1 += w0 * (float)p[1] + w1 * (float)r[1];
    a2 += w0 * (float)p[2] + w1 * (float)r[2];
    a3 += w0 * (float)p[3] + w1 * (float)r[3];
  }
  float4 o = {a0, a1, a2, a3};
  reinterpret_cast<float4*>(out)[(size_t)t * (NE / 4) + d] = o;
}

extern "C" void kernel_launch(void* const* d_in, const int* in_sizes, int n_in,
                              void* d_out, int out_size, void* d_ws, size_t ws_size,
                              hipStream_t stream) {
  const float* x     = (const float*)d_in[0];
  const float* noise = (const float*)d_in[1];
  const float* rw    = (const float*)d_in[2];
  const float* w1    = (const float*)d_in[3];
  const float* b1    = (const float*)d_in[4];
  const float* w2    = (const float*)d_in[5];
  const float* b2    = (const float*)d_in[6];
  float* out = (float*)d_out;

  constexpr int SP2 = 4;

  char* ws = (char*)d_ws;
  size_t off = 0;
  auto carve = [&](size_t bytes) { void* p = ws + off; off = (off + bytes + 255) & ~255ull; return p; };
  int*   offs     = (int*)carve((NEXP + 1) * 4);
  int*   sel      = (int*)carve(T_TOK * 2 * 4);
  float* wgt      = (float*)carve(T_TOK * 2 * 4);
  int*   pair_tok = (int*)carve(ROWS_PAD * 4);
  int*   slot_of  = (int*)carve(T_TOK * 2 * 4);
  int*   tiles    = (int*)carve(MAX_TILES * 2 * 4);
  int*   ntl      = (int*)carve(4);
  __hip_bfloat16* xg  = (__hip_bfloat16*)carve((size_t)ROWS_PAD * NE * 2);
  __hip_bfloat16* h   = (__hip_bfloat16*)carve((size_t)ROWS_PAD * DFF * 2);
  __hip_bfloat16* wt1 = (__hip_bfloat16*)carve((size_t)NEXP * NE * DFF * 2);
  __hip_bfloat16* wt2 = (__hip_bfloat16*)carve((size_t)NEXP * NE * DFF * 2);
  __hip_bfloat16* yb  = wt1;            // alias: wt1 dead after GEMM1 (yb 27.5MB <= 37.7MB)

  if (off > ws_size) {                  // diagnosable fail, not a fault
    hipMemsetAsync(d_out, 0, (size_t)out_size * sizeof(float), stream);
    return;
  }

  // router (512) | transpose w1 (4608) — independent, one dispatch
  router_t1_kernel<<<NB_RT + NB_T1, 256, 0, stream>>>(x, noise, rw, sel, wgt, w1, wt1);
  assign_kernel<<<1, 512, 0, stream>>>(sel, offs, pair_tok, slot_of, tiles, ntl);
  gather_kernel<<<T_TOK * 2, 256, 0, stream>>>(x, pair_tok, xg);

  // GEMM1 (480) | transpose w2 (4608) — T2 fills idle CUs during latency-bound G1
  g1_t2_kernel<<<NB_G1 + NB_T2, 256, 0, stream>>>(xg, wt1, b1, h, offs, tiles, ntl, w2, wt2);

  // GEMM2: K=3072, N=768 (NT=3), split-K x4 -> 480 blocks
  g2_kernel<<<MAX_TILES * SP2 * 3, 256, 0, stream>>>(h, wt2, b2, yb, offs, tiles, ntl);

  combine_kernel<SP2><<<T_TOK, 192, 0, stream>>>(yb, slot_of, wgt, out);
}

// Round 13
// 145.630 us; speedup vs baseline: 1.1127x; 1.1127x over previous
//
#include <hip/hip_runtime.h>
#include <hip/hip_bf16.h>

#define T_TOK 2048
#define NE 768
#define DFF 3072
#define NEXP 8
#define ROWS_PAD 4480
#define MAX_TILES 24   // 256-row tiles: ceil-sum <= 8 + 4096/256 = 24

typedef __attribute__((ext_vector_type(8))) __bf16 bf16x8;
typedef __attribute__((ext_vector_type(4))) __bf16 bf16x4;
typedef __attribute__((ext_vector_type(4))) float f32x4;

__device__ __forceinline__ float gelu_tanh(float v) {
  float u = 0.7978845608028654f * (v + 0.044715f * v * v * v);
  float e = __expf(-2.0f * fabsf(u));
  float t = (1.0f - e) / (1.0f + e);
  t = copysignf(t, u);
  return 0.5f * v * (1.0f + t);
}

// chunk involution (proven 0-conflict R10/R11): XOR low-3 of 16B-chunk id with row-pair id
__device__ __forceinline__ int swz_chunk(int c) {
  return (c & ~7) | ((c & 7) ^ ((c >> 3) & 7));
}

// ---------------- router: one wave per token, NO atomics ----------------
__global__ void router_kernel(const float* __restrict__ x,
                              const float* __restrict__ noise,
                              const float* __restrict__ rw,
                              int* __restrict__ sel, float* __restrict__ wgt) {
  int tok  = (blockIdx.x * blockDim.x + threadIdx.x) >> 6;
  int lane = threadIdx.x & 63;
  const float* xr = x + (size_t)tok * NE;
  float acc[NEXP];
#pragma unroll
  for (int e = 0; e < NEXP; e++) acc[e] = 0.f;
  for (int d = lane; d < NE; d += 64) {
    float xv = xr[d];
#pragma unroll
    for (int e = 0; e < NEXP; e++) acc[e] += xv * rw[e * NE + d];
  }
#pragma unroll
  for (int e = 0; e < NEXP; e++) {
#pragma unroll
    for (int off = 32; off > 0; off >>= 1) acc[e] += __shfl_xor(acc[e], off);
  }
  if (lane == 0) {
    float lg[NEXP];
#pragma unroll
    for (int e = 0; e < NEXP; e++) lg[e] = acc[e] + noise[tok * NEXP + e];
    int i0 = 0;
#pragma unroll
    for (int e = 1; e < NEXP; e++) if (lg[e] > lg[i0]) i0 = e;
    int i1 = (i0 == 0) ? 1 : 0;
#pragma unroll
    for (int e = 0; e < NEXP; e++) if (e != i0 && lg[e] > lg[i1]) i1 = e;
    float ex = __expf(lg[i1] - lg[i0]);
    float w0 = 1.f / (1.f + ex);
    sel[tok * 2]     = i0; sel[tok * 2 + 1] = i1;
    wgt[tok * 2]     = w0; wgt[tok * 2 + 1] = 1.f - w0;
  }
}

// ---------------- assignment + worklist (256-row tiles): 1 block, 8 waves ----------------
__global__ void assign_kernel(const int* __restrict__ sel,
                              int* __restrict__ offs, int* __restrict__ pair_tok,
                              int* __restrict__ slot_of, int* __restrict__ tiles,
                              int* __restrict__ ntl) {
  __shared__ int scnt[NEXP];
  __shared__ int soff[NEXP + 1];
  int e = threadIdx.x >> 6;
  int lane = threadIdx.x & 63;

  int count = 0;
  for (int t0 = 0; t0 < T_TOK; t0 += 64) {
    int t = t0 + lane;
    bool m = (sel[t * 2] == e) | (sel[t * 2 + 1] == e);
    count += __popcll(__ballot(m));
  }
  if (lane == 0) scnt[e] = count;
  __syncthreads();

  if (threadIdx.x == 0) {
    int s = 0;
    for (int k = 0; k < NEXP; k++) { soff[k] = s; s += scnt[k]; }
    soff[NEXP] = s;
    for (int i = 0; i <= NEXP; i++) offs[i] = soff[i];
    int k2 = 0;
    for (int k = 0; k < NEXP; k++)
      for (int r = soff[k]; r < soff[k + 1]; r += 256) {
        tiles[k2 * 2] = k; tiles[k2 * 2 + 1] = r; k2++;
      }
    *ntl = k2;
  }
  __syncthreads();

  int base = soff[e];
  for (int t0 = 0; t0 < T_TOK; t0 += 64) {
    int t = t0 + lane;
    int s0 = sel[t * 2], s1 = sel[t * 2 + 1];
    bool m0 = (s0 == e), m1 = (s1 == e);
    bool m = m0 | m1;
    unsigned long long mask = __ballot(m);
    int pos = __popcll(mask & ((1ull << lane) - 1ull));
    if (m) {
      int slot = base + pos;
      pair_tok[slot] = t;
      slot_of[t * 2 + (m0 ? 0 : 1)] = slot;
    }
    base += __popcll(mask);
  }
}

// ---------------- gather x rows -> bf16 ----------------
__global__ void gather_kernel(const float* __restrict__ x, const int* __restrict__ pair_tok,
                              __hip_bfloat16* __restrict__ xg) {
  int r = blockIdx.x;
  int tok = pair_tok[r];
  const float4* s = (const float4*)(x + (size_t)tok * NE);
  __hip_bfloat16* d = xg + (size_t)r * NE;
  int t = threadIdx.x;
  if (t < NE / 4) {
    float4 v = s[t];
    bf16x4 o;
    o[0] = (__bf16)__float2bfloat16(v.x); o[1] = (__bf16)__float2bfloat16(v.y);
    o[2] = (__bf16)__float2bfloat16(v.z); o[3] = (__bf16)__float2bfloat16(v.w);
    *reinterpret_cast<bf16x4*>(&d[t * 4]) = o;
  }
}

// ---------------- fp32 [E][K][N] -> bf16 [E][N][K], 64x64 tiles ----------------
__global__ void transpose_cvt(const float* __restrict__ src, __hip_bfloat16* __restrict__ dst,
                              int K, int N) {
  __shared__ __hip_bfloat16 tile[64 * 72];
  int ntk = K >> 6, ntn = N >> 6;
  int bid = blockIdx.x;
  int e = bid / (ntk * ntn);
  int rem = bid % (ntk * ntn);
  int tk = rem / ntn, tn = rem % ntn;
  const float* s = src + (size_t)e * K * N + (size_t)(tk * 64) * N + tn * 64;
  int t = threadIdx.x;
  int a = t & 15;
  int kp = t >> 4;
#pragma unroll
  for (int i = 0; i < 2; i++) {
    int k = 2 * kp + 32 * i;
    float4 v0 = *reinterpret_cast<const float4*>(&s[(size_t)k * N + 4 * a]);
    float4 v1 = *reinterpret_cast<const float4*>(&s[(size_t)(k + 1) * N + 4 * a]);
    const float* p0 = &v0.x; const float* p1 = &v1.x;
#pragma unroll
    for (int j = 0; j < 4; j++) {
      __hip_bfloat162 p;
      p.x = __float2bfloat16(p0[j]); p.y = __float2bfloat16(p1[j]);
      *reinterpret_cast<__hip_bfloat162*>(&tile[(4 * a + j) * 72 + k]) = p;
    }
  }
  __syncthreads();
  int n = t >> 3, g = t & 7;
  __hip_bfloat16* d = dst + (size_t)e * N * K + (size_t)(tn * 64) * K + tk * 64;
#pragma unroll
  for (int i = 0; i < 2; i++) {
    int row = n + 32 * i;
    bf16x8 v = *reinterpret_cast<const bf16x8*>(&tile[row * 72 + g * 8]);
    *reinterpret_cast<bf16x8*>(&d[(size_t)row * K + g * 8]) = v;
  }
}

// ---------------- grouped GEMM, 8-phase schedule (T2+T3+T4+T5): 256x256, BK=64,
//   8 waves, K-half staged half-tiles, counted vmcnt(4) twice/K-tile (never 0
//   mid-loop), setprio around MFMA, XCD-swizzled grid, LDS-bounce epilogue ------
// A: [rows][K] bf16. Bt: [E][N][K] bf16. DST: [SPLITS][ROWS_PAD][N] bf16.
// MODE 0: DST = bf16(gelu(acc+bias)); MODE 1: DST = bf16(acc + (sp==0 ? bias : 0)).
template <int K, int N, int MODE, int SPLITS>
__global__ __launch_bounds__(512, 1) void ffn_gemm8(
    const __hip_bfloat16* __restrict__ A, const __hip_bfloat16* __restrict__ Bt,
    const float* __restrict__ bias, __hip_bfloat16* __restrict__ DST,
    const int* __restrict__ offs, const int* __restrict__ tiles,
    const int* __restrict__ ntl) {
  constexpr int NT = N / 256;
  constexpr int KS = K / SPLITS;
  constexpr int NS = KS / 64;           // K-tiles (12 for both GEMMs)
  constexpr int NWG = MAX_TILES * SPLITS * NT;  // 288, %8 == 0

  // XCD-aware bijective swizzle; ti fastest (B-panel L2 locality per XCD)
  int b = blockIdx.x;
  int l = (b & 7) * (NWG >> 3) + (b >> 3);
  int ti = l % MAX_TILES;
  int r1 = l / MAX_TILES;
  int sp = r1 % SPLITS;
  int nt = r1 / SPLITS;
  if (ti >= *ntl) return;
  int e = tiles[ti * 2], row0 = tiles[ti * 2 + 1];
  int rend = offs[e + 1];
  int n0 = nt * 256;
  int kbeg = sp * KS;

  // LDS: A region 64KB [2 buf][2 khalf][256r x 32k], B region 64KB same
  __shared__ __align__(16) char smem[131072];
  char* smA = smem;
  char* smB = smem + 65536;

  int tid = threadIdx.x;
  int w = tid >> 6, l64 = tid & 63;
  int wr = w >> 2, wc = w & 3;          // 2x4 waves; wave tile 128 rows x 64 cols
  int r16 = l64 & 15, q = l64 >> 4;     // q = k-octet within 32k half

  f32x4 acc[8][4];
#pragma unroll
  for (int m = 0; m < 8; m++)
#pragma unroll
    for (int n = 0; n < 4; n++) acc[m][n] = (f32x4){0.f, 0.f, 0.f, 0.f};

  const __hip_bfloat16* Bte = Bt + (size_t)e * N * K;

  // issue one half-stage: 256 rows x 32 k = 16KB = 1024 chunks, 2 gloads/thread
  auto ISSUE = [&](int op, int buf, int kh, int tt) {
    char* dst0 = (op == 0 ? smA : smB) + (buf * 2 + kh) * 16384;
    const __hip_bfloat16* g =
        (op == 0) ? (A + (size_t)row0 * K) : (Bte + (size_t)n0 * K);
    int kbase = kbeg + tt * 64 + kh * 32;
#pragma unroll
    for (int i = 0; i < 2; i++) {
      int Lc = tid + 512 * i;
      int fc = swz_chunk(Lc);
      int row = fc >> 2, p = fc & 3;
      const __hip_bfloat16* src = g + (size_t)row * K + kbase + p * 8;
      __builtin_amdgcn_global_load_lds(
          (const __attribute__((address_space(1))) void*)src,
          (__attribute__((address_space(3))) void*)(dst0 + Lc * 16), 16, 0, 0);
    }
  };

  // prologue: tile 0's 4 halves; retire k0 halves, k1 stays in flight
  ISSUE(0, 0, 0, 0); ISSUE(1, 0, 0, 0); ISSUE(0, 0, 1, 0); ISSUE(1, 0, 1, 0);
  asm volatile("s_waitcnt vmcnt(4)" ::: "memory");
  __builtin_amdgcn_s_barrier();

  for (int t = 0; t < NS; t++) {
    const bool more = (t + 1 < NS);
    const char* rdA = smA + (t & 1) * 32768;
    const char* rdB = smB + (t & 1) * 32768;
    const int wb = (t + 1) & 1;
    bf16x8 aF[4], bF[4];

    // ---- ph1: kk=0, m-frags 0-3 (reads A-k0, B-k0) ----
#pragma unroll
    for (int m = 0; m < 4; m++)
      aF[m] = *reinterpret_cast<const bf16x8*>(
          rdA + swz_chunk((wr * 128 + m * 16 + r16) * 4 + q) * 16);
#pragma unroll
    for (int n = 0; n < 4; n++)
      bF[n] = *reinterpret_cast<const bf16x8*>(
          rdB + swz_chunk((wc * 64 + n * 16 + r16) * 4 + q) * 16);
    if (more) ISSUE(0, wb, 0, t + 1);
    __builtin_amdgcn_s_barrier();
    __builtin_amdgcn_s_setprio(1);
#pragma unroll
    for (int m = 0; m < 4; m++)
#pragma unroll
      for (int n = 0; n < 4; n++)
        acc[m][n] = __builtin_amdgcn_mfma_f32_16x16x32_bf16(aF[m], bF[n], acc[m][n], 0, 0, 0);
    __builtin_amdgcn_s_setprio(0);
    __builtin_amdgcn_s_barrier();

    // ---- ph2: kk=0, m-frags 4-7 (bF reused) ----
#pragma unroll
    for (int m = 0; m < 4; m++)
      aF[m] = *reinterpret_cast<const bf16x8*>(
          rdA + swz_chunk((wr * 128 + (4 + m) * 16 + r16) * 4 + q) * 16);
    if (more) ISSUE(1, wb, 0, t + 1);
    __builtin_amdgcn_s_barrier();
    __builtin_amdgcn_s_setprio(1);
#pragma unroll
    for (int m = 0; m < 4; m++)
#pragma unroll
      for (int n = 0; n < 4; n++)
        acc[4 + m][n] = __builtin_amdgcn_mfma_f32_16x16x32_bf16(aF[m], bF[n], acc[4 + m][n], 0, 0, 0);
    __builtin_amdgcn_s_setprio(0);
    if (more) asm volatile("s_waitcnt vmcnt(4)" ::: "memory");   // retire k1 halves of t
    else      asm volatile("s_waitcnt vmcnt(0)" ::: "memory");
    __builtin_amdgcn_s_barrier();

    // ---- ph3: kk=1, m-frags 0-3 (reads A-k1, B-k1) ----
#pragma unroll
    for (int m = 0; m < 4; m++)
      aF[m] = *reinterpret_cast<const bf16x8*>(
          rdA + 16384 + swz_chunk((wr * 128 + m * 16 + r16) * 4 + q) * 16);
#pragma unroll
    for (int n = 0; n < 4; n++)
      bF[n] = *reinterpret_cast<const bf16x8*>(
          rdB + 16384 + swz_chunk((wc * 64 + n * 16 + r16) * 4 + q) * 16);
    if (more) ISSUE(0, wb, 1, t + 1);
    __builtin_amdgcn_s_barrier();
    __builtin_amdgcn_s_setprio(1);
#pragma unroll
    for (int m = 0; m < 4; m++)
#pragma unroll
      for (int n = 0; n < 4; n++)
        acc[m][n] = __builtin_amdgcn_mfma_f32_16x16x32_bf16(aF[m], bF[n], acc[m][n], 0, 0, 0);
    __builtin_amdgcn_s_setprio(0);
    __builtin_amdgcn_s_barrier();

    // ---- ph4: kk=1, m-frags 4-7 ----
#pragma unroll
    for (int m = 0; m < 4; m++)
      aF[m] = *reinterpret_cast<const bf16x8*>(
          rdA + 16384 + swz_chunk((wr * 128 + (4 + m) * 16 + r16) * 4 + q) * 16);
    if (more) ISSUE(1, wb, 1, t + 1);
    __builtin_amdgcn_s_barrier();
    __builtin_amdgcn_s_setprio(1);
#pragma unroll
    for (int m = 0; m < 4; m++)
#pragma unroll
      for (int n = 0; n < 4; n++)
        acc[4 + m][n] = __builtin_amdgcn_mfma_f32_16x16x32_bf16(aF[m], bF[n], acc[4 + m][n], 0, 0, 0);
    __builtin_amdgcn_s_setprio(0);
    if (more) asm volatile("s_waitcnt vmcnt(4)" ::: "memory");   // retire k0 halves of t+1
    else      asm volatile("s_waitcnt vmcnt(0)" ::: "memory");
    __builtin_amdgcn_s_barrier();
  }

  // ---- epilogue via LDS bounce: 4 phases of 64 rows x 256 cols (f32 [64][264]) ----
  float* ldsF = (float*)smem;
  __hip_bfloat16* dst = DST + (size_t)sp * ROWS_PAD * N;
#pragma unroll
  for (int hh = 0; hh < 4; hh++) {
    __syncthreads();
    if (wr == (hh >> 1)) {
      int mbase = (hh & 1) * 4;
#pragma unroll
      for (int mi = 0; mi < 4; mi++)
#pragma unroll
        for (int n = 0; n < 4; n++)
#pragma unroll
          for (int rg = 0; rg < 4; rg++)
            ldsF[(mi * 16 + q * 4 + rg) * 264 + wc * 64 + n * 16 + r16] =
                acc[mbase + mi][n][rg];
    }
    __syncthreads();
#pragma unroll
    for (int i = 0; i < 4; i++) {
      int s = tid + 512 * i;            // 2048 spans of 8 f32
      int r = s >> 5, c8 = s & 31;
      int rr = row0 + hh * 64 + r;
      if (rr < rend) {
        const float* src = &ldsF[r * 264 + c8 * 8];
        float4 v0 = *reinterpret_cast<const float4*>(src);
        float4 v1 = *reinterpret_cast<const float4*>(src + 4);
        const float* bp = &bias[e * N + n0 + c8 * 8];
        float4 bb0 = *reinterpret_cast<const float4*>(bp);
        float4 bb1 = *reinterpret_cast<const float4*>(bp + 4);
        float vv[8]  = {v0.x, v0.y, v0.z, v0.w, v1.x, v1.y, v1.z, v1.w};
        float bbv[8] = {bb0.x, bb0.y, bb0.z, bb0.w, bb1.x, bb1.y, bb1.z, bb1.w};
        bf16x8 o;
#pragma unroll
        for (int j = 0; j < 8; j++) {
          float val;
          if (MODE == 0) val = gelu_tanh(vv[j] + bbv[j]);
          else           val = vv[j] + (sp == 0 ? bbv[j] : 0.f);
          o[j] = (__bf16)__float2bfloat16(val);
        }
        *reinterpret_cast<bf16x8*>(&dst[(size_t)rr * N + n0 + c8 * 8]) = o;
      }
    }
  }
}

// ---------------- combine ----------------
template <int SPLITS>
__global__ void combine_kernel(const __hip_bfloat16* __restrict__ yb,
                               const int* __restrict__ slot_of,
                               const float* __restrict__ wgt,
                               float* __restrict__ out) {
  int t = blockIdx.x;
  int d = threadIdx.x;
  int s0 = slot_of[2 * t], s1 = slot_of[2 * t + 1];
  float w0 = wgt[2 * t], w1 = wgt[2 * t + 1];
  float a0 = 0.f, a1 = 0.f, a2 = 0.f, a3 = 0.f;
#pragma unroll
  for (int sp = 0; sp < SPLITS; sp++) {
    bf16x4 p = reinterpret_cast<const bf16x4*>(yb + (size_t)(sp * ROWS_PAD + s0) * NE)[d];
    bf16x4 r = reinterpret_cast<const bf16x4*>(yb + (size_t)(sp * ROWS_PAD + s1) * NE)[d];
    a0 += w0 * (float)p[0] + w1 * (float)r[0];
    a1 += w0 * (float)p[1] + w1 * (float)r[1];
    a2 += w0 * (float)p[2] + w1 * (float)r[2];
    a3 += w0 * (float)p[3] + w1 * (float)r[3];
  }
  float4 o = {a0, a1, a2, a3};
  reinterpret_cast<float4*>(out)[(size_t)t * (NE / 4) + d] = o;
}

extern "C" void kernel_launch(void* const* d_in, const int* in_sizes, int n_in,
                              void* d_out, int out_size, void* d_ws, size_t ws_size,
                              hipStream_t stream) {
  const float* x     = (const float*)d_in[0];
  const float* noise = (const float*)d_in[1];
  const float* rw    = (const float*)d_in[2];
  const float* w1    = (const float*)d_in[3];
  const float* b1    = (const float*)d_in[4];
  const float* w2    = (const float*)d_in[5];
  const float* b2    = (const float*)d_in[6];
  float* out = (float*)d_out;

  constexpr int SP2 = 4;

  char* ws = (char*)d_ws;
  size_t off = 0;
  auto carve = [&](size_t bytes) { void* p = ws + off; off = (off + bytes + 255) & ~255ull; return p; };
  int*   offs     = (int*)carve((NEXP + 1) * 4);
  int*   sel      = (int*)carve(T_TOK * 2 * 4);
  float* wgt      = (float*)carve(T_TOK * 2 * 4);
  int*   pair_tok = (int*)carve(ROWS_PAD * 4);
  int*   slot_of  = (int*)carve(T_TOK * 2 * 4);
  int*   tiles    = (int*)carve(MAX_TILES * 2 * 4);
  int*   ntl      = (int*)carve(4);
  __hip_bfloat16* xg  = (__hip_bfloat16*)carve((size_t)ROWS_PAD * NE * 2);
  __hip_bfloat16* h   = (__hip_bfloat16*)carve((size_t)ROWS_PAD * DFF * 2);
  __hip_bfloat16* yb  = (__hip_bfloat16*)carve((size_t)SP2 * ROWS_PAD * NE * 2);
  __hip_bfloat16* wt  = (__hip_bfloat16*)carve((size_t)NEXP * NE * DFF * 2);

  if (off > ws_size) {                  // diagnosable fail, not a fault
    hipMemsetAsync(d_out, 0, (size_t)out_size * sizeof(float), stream);
    return;
  }

  router_kernel<<<(T_TOK * 64) / 256, 256, 0, stream>>>(x, noise, rw, sel, wgt);
  assign_kernel<<<1, 512, 0, stream>>>(sel, offs, pair_tok, slot_of, tiles, ntl);
  gather_kernel<<<T_TOK * 2, 256, 0, stream>>>(x, pair_tok, xg);

  // w1 [E][768][3072] -> wt [E][3072][768]; GEMM1: K=768, N=3072 (NS=12)
  transpose_cvt<<<NEXP * (NE / 64) * (DFF / 64), 256, 0, stream>>>(w1, wt, NE, DFF);
  ffn_gemm8<NE, DFF, 0, 1><<<MAX_TILES * 1 * (DFF / 256), 512, 0, stream>>>(
      xg, wt, b1, h, offs, tiles, ntl);

  // w2 [E][3072][768] -> wt [E][768][3072]; GEMM2: K=3072, N=768, split-K x4 (NS=12)
  transpose_cvt<<<NEXP * (DFF / 64) * (NE / 64), 256, 0, stream>>>(w2, wt, DFF, NE);
  ffn_gemm8<DFF, NE, 1, SP2><<<MAX_TILES * SP2 * (NE / 256), 512, 0, stream>>>(
      h, wt, b2, yb, offs, tiles, ntl);

  combine_kernel<SP2><<<T_TOK, 192, 0, stream>>>(yb, slot_of, wgt, out);
}